// Round 1
// baseline (285.508 us; speedup 1.0000x reference)
//
#include <hip/hip_runtime.h>
#include <math.h>

#define Ss 1024
#define Dd 1024
#define Hh 16
#define Kk 64

typedef __bf16 bf16x8 __attribute__((ext_vector_type(8)));
typedef __bf16 bf16x4 __attribute__((ext_vector_type(4)));
typedef float  f32x4  __attribute__((ext_vector_type(4)));

#define MFMA16(a, b, c) __builtin_amdgcn_mfma_f32_16x16x32_bf16(a, b, c, 0, 0, 0)

// ws element offsets (bf16 units)
#define XB_E   8388608u
#define WT_E   3145728u
#define WOT_E  1048576u
#define QKV_E  8388608u

// global -> LDS DMA, 16B per lane. LDS dest = readfirstlane(l) + lane*16,
// which matches our linear [row][col] staging layout exactly (byte t*16).
typedef __attribute__((address_space(1))) const void gas_void;
typedef __attribute__((address_space(3))) void las_void;
__device__ __forceinline__ void gll16(const __bf16* g, __bf16* l) {
    __builtin_amdgcn_global_load_lds((gas_void*)g, (las_void*)l, 16, 0, 0);
}

// ---------------------------------------------------------------------------
// prep: z<4 -> transpose+cast weight matrix z; z==4 -> cast x to bf16
// ---------------------------------------------------------------------------
__global__ __launch_bounds__(256) void prep(
    const float* __restrict__ x,
    const float* __restrict__ Wq, const float* __restrict__ Wk,
    const float* __restrict__ Wv, const float* __restrict__ Wo,
    __bf16* __restrict__ xb, __bf16* __restrict__ WT, __bf16* __restrict__ WoT)
{
    __shared__ float tile[64][65];
    const int z = blockIdx.z;
    const int t = threadIdx.x;

    if (z == 4) {   // x cast: 256 blocks, 32 rows x 1024 cols each
        size_t blk = blockIdx.y * 16 + blockIdx.x;
        const float4* src = (const float4*)(x + blk * 32768);
        bf16x4* dst = (bf16x4*)(((__bf16*)xb) + blk * 32768);
        #pragma unroll
        for (int u = 0; u < 32; ++u) {
            float4 v = src[u * 256 + t];
            dst[u * 256 + t] =
                (bf16x4){(__bf16)v.x, (__bf16)v.y, (__bf16)v.z, (__bf16)v.w};
        }
        return;
    }

    const float* src = (z == 0) ? Wq : (z == 1) ? Wk : (z == 2) ? Wv : Wo;
    __bf16* dst = (z < 3) ? (WT + (size_t)z * 1048576) : WoT;

    int r0 = blockIdx.y * 64, c0 = blockIdx.x * 64;
    int rr = t >> 2, cg = (t & 3) * 16;

    #pragma unroll
    for (int u = 0; u < 4; ++u) {
        float4 v = *(const float4*)(src + (size_t)(r0 + rr) * 1024 + c0 + cg + u * 4);
        tile[rr][cg + u * 4 + 0] = v.x;
        tile[rr][cg + u * 4 + 1] = v.y;
        tile[rr][cg + u * 4 + 2] = v.z;
        tile[rr][cg + u * 4 + 3] = v.w;
    }
    __syncthreads();
    bf16x8 o0, o1;
    #pragma unroll
    for (int jj = 0; jj < 8; ++jj) o0[jj] = (__bf16)tile[cg + jj][rr];
    #pragma unroll
    for (int jj = 0; jj < 8; ++jj) o1[jj] = (__bf16)tile[cg + 8 + jj][rr];
    __bf16* dp = dst + (size_t)(c0 + rr) * 1024 + r0 + cg;
    *(bf16x8*)dp = o0;
    *(bf16x8*)(dp + 8) = o1;
}

// ---------------------------------------------------------------------------
// bf16 MFMA GEMM, C = A(MxK) * Bt(NxK)^T. 128x128 tile, BK=32.
// m97 structure: global_load_lds (16B/lane DMA) into ping-pong LDS buffers,
// ONE barrier per K-iter:
//   barrier (drains DMA into buf p, fences reads of buf p^1)
//   -> issue DMA(i+1) into buf p^1 -> compute(i) from buf p
// DMA is in flight across the whole compute phase.
// mode 0: QKV epilogue (Q pre-scaled by 1/8); mode 1: fp32 out + bias.
// ---------------------------------------------------------------------------
__global__ __launch_bounds__(256) void gemm_bt(
    const __bf16* __restrict__ A, const __bf16* __restrict__ Bt, int mode,
    __bf16* __restrict__ qb, __bf16* __restrict__ kb, __bf16* __restrict__ vb,
    const float* __restrict__ bq, const float* __restrict__ bk,
    const float* __restrict__ bv,
    float* __restrict__ outf, const float* __restrict__ bo)
{
    __shared__ __align__(16) __bf16 As[2][128][32];
    __shared__ __align__(16) __bf16 Bs[2][128][32];

    const int t = threadIdx.x;
    const int wave = t >> 6, lane = t & 63;
    const int quad = lane >> 4, l16 = lane & 15;
    const int wm = wave >> 1, wn = wave & 1;
    const int m0 = blockIdx.y * 128, n0 = blockIdx.x * 128;

    const int sr = t >> 2;          // staging row 0..63
    const int sc = (t & 3) * 8;     // staging col (bf16 units)

    f32x4 acc[4][4];
    #pragma unroll
    for (int i = 0; i < 4; ++i)
        #pragma unroll
        for (int j = 0; j < 4; ++j) acc[i][j] = (f32x4){0.f, 0.f, 0.f, 0.f};

    const __bf16* pa0 = A + (size_t)(m0 + sr) * 1024 + sc;
    const __bf16* pa1 = pa0 + 64 * 1024;
    const __bf16* pb0 = Bt + (size_t)(n0 + sr) * 1024 + sc;
    const __bf16* pb1 = pb0 + 64 * 1024;

    // per-thread LDS staging address (byte t*16 within each half-tile);
    // readfirstlane gives the wave-uniform base, HW adds lane*16.
    __bf16* lA = &As[0][0][0] + t * 8;
    __bf16* lB = &Bs[0][0][0] + t * 8;

#define STAGE(p, kk) do {                       \
        gll16(pa0 + (kk), lA + (p) * 4096);     \
        gll16(pa1 + (kk), lA + (p) * 4096 + 2048); \
        gll16(pb0 + (kk), lB + (p) * 4096);     \
        gll16(pb1 + (kk), lB + (p) * 4096 + 2048); \
    } while (0)

    STAGE(0, 0);

    for (int k0 = 0; k0 < 1024; k0 += 32) {
        const int p = (k0 >> 5) & 1;
        // drains vmcnt(0): DMA into buf p complete & visible to all waves;
        // also fences all waves' ds_reads of buf p^1 from the previous iter.
        __syncthreads();

        const int kn = k0 + 32;
        if (kn < 1024) STAGE(p ^ 1, kn);   // in flight across compute below

        bf16x8 af[4], bfr[4];
        #pragma unroll
        for (int i = 0; i < 4; ++i)
            af[i] = *(const bf16x8*)&As[p][wm * 64 + i * 16 + l16][quad * 8];
        #pragma unroll
        for (int j = 0; j < 4; ++j)
            bfr[j] = *(const bf16x8*)&Bs[p][wn * 64 + j * 16 + l16][quad * 8];
        #pragma unroll
        for (int i = 0; i < 4; ++i)
            #pragma unroll
            for (int j = 0; j < 4; ++j)
                acc[i][j] = MFMA16(af[i], bfr[j], acc[i][j]);
    }
#undef STAGE

    if (mode == 0) {
        const int z = n0 >> 10;
        const float* bias = (z == 0) ? bq : (z == 1) ? bk : bv;
        const float sc2 = (z == 0) ? 0.125f : 1.0f;   // fold score scale into Q
        #pragma unroll
        for (int i = 0; i < 4; ++i) {
            int row = m0 + wm * 64 + i * 16 + quad * 4;
            int b = row >> 10, s = row & 1023;
            #pragma unroll
            for (int j = 0; j < 4; ++j) {
                int n1 = (n0 + wn * 64 + j * 16 + l16) & 1023;
                int h = n1 >> 6, ch = n1 & 63;
                float bia = bias[n1];
                if (z < 2) {
                    __bf16* dst = ((z == 0) ? qb : kb)
                        + ((size_t)(b * Hh + h) * Ss + s) * Kk + ch;
                    #pragma unroll
                    for (int r = 0; r < 4; ++r)
                        dst[(size_t)r * Kk] = (__bf16)((acc[i][j][r] + bia) * sc2);
                } else {
                    bf16x4 o;
                    #pragma unroll
                    for (int r = 0; r < 4; ++r) o[r] = (__bf16)(acc[i][j][r] + bia);
                    *(bf16x4*)(vb + ((size_t)(b * Hh + h) * Kk + ch) * Ss + s) = o;
                }
            }
        }
    } else {
        #pragma unroll
        for (int i = 0; i < 4; ++i) {
            int row = m0 + wm * 64 + i * 16 + quad * 4;
            #pragma unroll
            for (int j = 0; j < 4; ++j) {
                int n = n0 + wn * 64 + j * 16 + l16;
                float bia = bo[n];
                #pragma unroll
                for (int r = 0; r < 4; ++r)
                    outf[(size_t)(row + r) * 1024 + n] = acc[i][j][r] + bia;
            }
        }
    }
}

// ---------------------------------------------------------------------------
// Flash attention: fixed-base softmax (scores bounded => no max tracking),
// wave-private P (no barrier), 32 q/wave, VGPR prefetch of next K/V tile.
// Mask: p = mq ? (mk ? exp(s) : 0) : 1 — exactly matches reference semantics.
// ---------------------------------------------------------------------------
__global__ __launch_bounds__(256) void attn(
    const __bf16* __restrict__ qb, const __bf16* __restrict__ kb,
    const __bf16* __restrict__ vb, const int* __restrict__ mask,
    __bf16* __restrict__ ctx)
{
    const int bh = blockIdx.x;
    const int q0 = blockIdx.y * 128;
    const int b  = bh >> 4;
    const int h  = bh & 15;
    const size_t base = (size_t)bh * Ss * Kk;

    __shared__ __align__(16) __bf16 Qs[128][72];
    __shared__ __align__(16) __bf16 Ks[64][72];
    __shared__ __align__(16) __bf16 VTs[64][72];
    __shared__ __align__(16) __bf16 Ps[4][32][72];
    __shared__ float mkf[1024];

    const int t    = threadIdx.x;
    const int wave = t >> 6, lane = t & 63;
    const int quad = lane >> 4, l16 = lane & 15;
    const int qbase = wave * 32;

    #pragma unroll
    for (int p = 0; p < 4; ++p) {
        int idx = t + p * 256;
        int r = idx >> 3, g = idx & 7;
        *(bf16x8*)&Qs[r][g * 8] =
            *(const bf16x8*)(qb + base + (size_t)(q0 + r) * Kk + g * 8);
    }
    {
        int4 mi = *(const int4*)(mask + b * Ss + t * 4);
        mkf[t * 4 + 0] = (float)mi.x;
        mkf[t * 4 + 1] = (float)mi.y;
        mkf[t * 4 + 2] = (float)mi.z;
        mkf[t * 4 + 3] = (float)mi.w;
    }

    const int r0 = t >> 3, c0 = (t & 7) * 8;
    bf16x8 kr0, kr1, vr0, vr1;
    kr0 = *(const bf16x8*)(kb + base + (size_t)(r0) * Kk + c0);
    kr1 = *(const bf16x8*)(kb + base + (size_t)(r0 + 32) * Kk + c0);
    vr0 = *(const bf16x8*)(vb + base + (size_t)(r0) * Ss + c0);
    vr1 = *(const bf16x8*)(vb + base + (size_t)(r0 + 32) * Ss + c0);

    __syncthreads();

    bf16x8 aq[2][2];
    #pragma unroll
    for (int rg = 0; rg < 2; ++rg) {
        aq[rg][0] = *(const bf16x8*)&Qs[qbase + rg * 16 + l16][quad * 8];
        aq[rg][1] = *(const bf16x8*)&Qs[qbase + rg * 16 + l16][32 + quad * 8];
    }
    float mqf[2][4], omqf[2][4];
    #pragma unroll
    for (int rg = 0; rg < 2; ++rg)
        #pragma unroll
        for (int i = 0; i < 4; ++i) {
            float m = mkf[q0 + qbase + rg * 16 + quad * 4 + i];
            mqf[rg][i] = m; omqf[rg][i] = 1.0f - m;
        }

    f32x4 O[2][4];
    float lsum[2][4];
    #pragma unroll
    for (int rg = 0; rg < 2; ++rg)
        #pragma unroll
        for (int nb = 0; nb < 4; ++nb) O[rg][nb] = (f32x4){0.f, 0.f, 0.f, 0.f};
    #pragma unroll
    for (int rg = 0; rg < 2; ++rg)
        #pragma unroll
        for (int i = 0; i < 4; ++i) lsum[rg][i] = 0.f;

    for (int kt = 0; kt < Ss; kt += 64) {
        __syncthreads();
        *(bf16x8*)&Ks[r0][c0] = kr0;
        *(bf16x8*)&Ks[r0 + 32][c0] = kr1;
        *(bf16x8*)&VTs[r0][c0] = vr0;
        *(bf16x8*)&VTs[r0 + 32][c0] = vr1;
        __syncthreads();

        int ktn = kt + 64;
        if (ktn < Ss) {
            kr0 = *(const bf16x8*)(kb + base + (size_t)(ktn + r0) * Kk + c0);
            kr1 = *(const bf16x8*)(kb + base + (size_t)(ktn + r0 + 32) * Kk + c0);
            vr0 = *(const bf16x8*)(vb + base + (size_t)(r0) * Ss + ktn + c0);
            vr1 = *(const bf16x8*)(vb + base + (size_t)(r0 + 32) * Ss + ktn + c0);
        }

        float mkv[4];
        #pragma unroll
        for (int nb = 0; nb < 4; ++nb) mkv[nb] = mkf[kt + nb * 16 + l16];

        bf16x8 kb0[4], kb1[4];
        #pragma unroll
        for (int nb = 0; nb < 4; ++nb) {
            kb0[nb] = *(const bf16x8*)&Ks[nb * 16 + l16][quad * 8];
            kb1[nb] = *(const bf16x8*)&Ks[nb * 16 + l16][32 + quad * 8];
        }

        f32x4 s[2][4];
        #pragma unroll
        for (int rg = 0; rg < 2; ++rg)
            #pragma unroll
            for (int nb = 0; nb < 4; ++nb) {
                f32x4 a = (f32x4){0.f, 0.f, 0.f, 0.f};
                a = MFMA16(aq[rg][0], kb0[nb], a);
                a = MFMA16(aq[rg][1], kb1[nb], a);
                s[rg][nb] = a;
            }

        #pragma unroll
        for (int rg = 0; rg < 2; ++rg)
            #pragma unroll
            for (int i = 0; i < 4; ++i) {
                float ls = 0.f;
                #pragma unroll
                for (int nb = 0; nb < 4; ++nb) {
                    float p = __expf(s[rg][nb][i]) * mkv[nb];
                    p = p * mqf[rg][i] + omqf[rg][i];
                    Ps[wave][rg * 16 + quad * 4 + i][nb * 16 + l16] = (__bf16)p;
                    ls += p;
                }
                lsum[rg][i] += ls;
            }

        bf16x8 ap0[2], ap1[2];
        #pragma unroll
        for (int rg = 0; rg < 2; ++rg) {
            ap0[rg] = *(const bf16x8*)&Ps[wave][rg * 16 + l16][quad * 8];
            ap1[rg] = *(const bf16x8*)&Ps[wave][rg * 16 + l16][32 + quad * 8];
        }
        #pragma unroll
        for (int nb = 0; nb < 4; ++nb) {
            bf16x8 vb0 = *(const bf16x8*)&VTs[nb * 16 + l16][quad * 8];
            bf16x8 vb1 = *(const bf16x8*)&VTs[nb * 16 + l16][32 + quad * 8];
            #pragma unroll
            for (int rg = 0; rg < 2; ++rg) {
                O[rg][nb] = MFMA16(ap0[rg], vb0, O[rg][nb]);
                O[rg][nb] = MFMA16(ap1[rg], vb1, O[rg][nb]);
            }
        }
    }

    #pragma unroll
    for (int rg = 0; rg < 2; ++rg)
        #pragma unroll
        for (int i = 0; i < 4; ++i) {
            float l = lsum[rg][i];
            l += __shfl_xor(l, 1);
            l += __shfl_xor(l, 2);
            l += __shfl_xor(l, 4);
            l += __shfl_xor(l, 8);
            float inv = 1.0f / l;
            int srow = q0 + qbase + rg * 16 + quad * 4 + i;
            __bf16* dst = ctx + ((size_t)(b * Ss + srow) * Hh + h) * Kk;
            #pragma unroll
            for (int nb = 0; nb < 4; ++nb)
                dst[nb * 16 + l16] = (__bf16)(O[rg][nb][i] * inv);
        }
}

extern "C" void kernel_launch(void* const* d_in, const int* in_sizes, int n_in,
                              void* d_out, int out_size, void* d_ws, size_t ws_size,
                              hipStream_t stream) {
    const float* x    = (const float*)d_in[0];
    const int*   mask = (const int*)d_in[1];
    const float* Wq   = (const float*)d_in[2];
    const float* bq   = (const float*)d_in[3];
    const float* Wk   = (const float*)d_in[4];
    const float* bk   = (const float*)d_in[5];
    const float* Wv   = (const float*)d_in[6];
    const float* bv   = (const float*)d_in[7];
    const float* Wo   = (const float*)d_in[8];
    const float* bo   = (const float*)d_in[9];

    __bf16* xb   = (__bf16*)d_ws;
    __bf16* WT   = xb + XB_E;
    __bf16* WoT  = WT + WT_E;
    __bf16* qb   = WoT + WOT_E;
    __bf16* kb   = qb + QKV_E;
    __bf16* vb   = kb + QKV_E;
    __bf16* ctxb = vb + QKV_E;
    float* out = (float*)d_out;

    prep<<<dim3(16, 16, 5), 256, 0, stream>>>(x, Wq, Wk, Wv, Wo, xb, WT, WoT);
    gemm_bt<<<dim3(24, 64), 256, 0, stream>>>(xb, WT, 0, qb, kb, vb,
                                              bq, bk, bv, nullptr, nullptr);
    attn<<<dim3(128, 8), 256, 0, stream>>>(qb, kb, vb, mask, ctxb);
    gemm_bt<<<dim3(8, 64), 256, 0, stream>>>(ctxb, WoT, 1, nullptr, nullptr,
                                             nullptr, nullptr, nullptr, nullptr,
                                             out, bo);
}

// Round 2
// 271.672 us; speedup vs baseline: 1.0509x; 1.0509x over previous
//
#include <hip/hip_runtime.h>
#include <math.h>

#define Ss 1024
#define Dd 1024
#define Hh 16
#define Kk 64

typedef __bf16 bf16x8 __attribute__((ext_vector_type(8)));
typedef __bf16 bf16x4 __attribute__((ext_vector_type(4)));
typedef float  f32x4  __attribute__((ext_vector_type(4)));

#define MFMA16(a, b, c) __builtin_amdgcn_mfma_f32_16x16x32_bf16(a, b, c, 0, 0, 0)

// ws element offsets (bf16 units)
#define XB_E   8388608u
#define WT_E   3145728u
#define WOT_E  1048576u
#define QKV_E  8388608u

// v_exp_f32 is natively 2^x; log2(e) is folded into the Q scale in gemm.
__device__ __forceinline__ float exp2_hw(float x) {
    float r; asm("v_exp_f32 %0, %1" : "=v"(r) : "v"(x)); return r;
}

// ---------------------------------------------------------------------------
// prep: z<4 -> transpose+cast weight matrix z; z==4 -> cast x to bf16
// ---------------------------------------------------------------------------
__global__ __launch_bounds__(256) void prep(
    const float* __restrict__ x,
    const float* __restrict__ Wq, const float* __restrict__ Wk,
    const float* __restrict__ Wv, const float* __restrict__ Wo,
    __bf16* __restrict__ xb, __bf16* __restrict__ WT, __bf16* __restrict__ WoT)
{
    __shared__ float tile[64][65];
    const int z = blockIdx.z;
    const int t = threadIdx.x;

    if (z == 4) {   // x cast: 256 blocks, 32 rows x 1024 cols each
        size_t blk = blockIdx.y * 16 + blockIdx.x;
        const float4* src = (const float4*)(x + blk * 32768);
        bf16x4* dst = (bf16x4*)(((__bf16*)xb) + blk * 32768);
        #pragma unroll
        for (int u = 0; u < 32; ++u) {
            float4 v = src[u * 256 + t];
            dst[u * 256 + t] =
                (bf16x4){(__bf16)v.x, (__bf16)v.y, (__bf16)v.z, (__bf16)v.w};
        }
        return;
    }

    const float* src = (z == 0) ? Wq : (z == 1) ? Wk : (z == 2) ? Wv : Wo;
    __bf16* dst = (z < 3) ? (WT + (size_t)z * 1048576) : WoT;

    int r0 = blockIdx.y * 64, c0 = blockIdx.x * 64;
    int rr = t >> 2, cg = (t & 3) * 16;

    #pragma unroll
    for (int u = 0; u < 4; ++u) {
        float4 v = *(const float4*)(src + (size_t)(r0 + rr) * 1024 + c0 + cg + u * 4);
        tile[rr][cg + u * 4 + 0] = v.x;
        tile[rr][cg + u * 4 + 1] = v.y;
        tile[rr][cg + u * 4 + 2] = v.z;
        tile[rr][cg + u * 4 + 3] = v.w;
    }
    __syncthreads();
    bf16x8 o0, o1;
    #pragma unroll
    for (int jj = 0; jj < 8; ++jj) o0[jj] = (__bf16)tile[cg + jj][rr];
    #pragma unroll
    for (int jj = 0; jj < 8; ++jj) o1[jj] = (__bf16)tile[cg + 8 + jj][rr];
    __bf16* dp = dst + (size_t)(c0 + rr) * 1024 + r0 + cg;
    *(bf16x8*)dp = o0;
    *(bf16x8*)(dp + 8) = o1;
}

// ---------------------------------------------------------------------------
// bf16 MFMA GEMM, C = A(MxK) * Bt(NxK)^T. 128x128 tile, BK=32.
// Ping-pong LDS double buffer, ONE barrier per K-iter, VGPR-prefetch staging:
//   W(i) -> barrier -> issue L(i+1) -> compute(i)
// (Reg-staged path measured 84 us vs 106 us for global_load_lds here: per-wave
// vmcnt waits beat the block-wide vmcnt(0) drain at ~2 blocks/CU occupancy.)
// mode 0: QKV epilogue (Q pre-scaled by log2e/8); mode 1: fp32 out + bias.
// ---------------------------------------------------------------------------
__global__ __launch_bounds__(256) void gemm_bt(
    const __bf16* __restrict__ A, const __bf16* __restrict__ Bt, int mode,
    __bf16* __restrict__ qb, __bf16* __restrict__ kb, __bf16* __restrict__ vb,
    const float* __restrict__ bq, const float* __restrict__ bk,
    const float* __restrict__ bv,
    float* __restrict__ outf, const float* __restrict__ bo)
{
    __shared__ __align__(16) __bf16 As[2][128][32];
    __shared__ __align__(16) __bf16 Bs[2][128][32];

    const int t = threadIdx.x;
    const int wave = t >> 6, lane = t & 63;
    const int quad = lane >> 4, l16 = lane & 15;
    const int wm = wave >> 1, wn = wave & 1;
    const int m0 = blockIdx.y * 128, n0 = blockIdx.x * 128;

    const int sr = t >> 2;          // staging row 0..63
    const int sc = (t & 3) * 8;     // staging col (bf16 units)

    f32x4 acc[4][4];
    #pragma unroll
    for (int i = 0; i < 4; ++i)
        #pragma unroll
        for (int j = 0; j < 4; ++j) acc[i][j] = (f32x4){0.f, 0.f, 0.f, 0.f};

    const __bf16* pa0 = A + (size_t)(m0 + sr) * 1024 + sc;
    const __bf16* pa1 = A + (size_t)(m0 + sr + 64) * 1024 + sc;
    const __bf16* pb0 = Bt + (size_t)(n0 + sr) * 1024 + sc;
    const __bf16* pb1 = Bt + (size_t)(n0 + sr + 64) * 1024 + sc;

    // preload k-chunk 0
    bf16x8 ra0 = *(const bf16x8*)(pa0);
    bf16x8 ra1 = *(const bf16x8*)(pa1);
    bf16x8 rb0 = *(const bf16x8*)(pb0);
    bf16x8 rb1 = *(const bf16x8*)(pb1);

    for (int k0 = 0; k0 < 1024; k0 += 32) {
        const int p = (k0 >> 5) & 1;
        *(bf16x8*)&As[p][sr][sc] = ra0;
        *(bf16x8*)&As[p][sr + 64][sc] = ra1;
        *(bf16x8*)&Bs[p][sr][sc] = rb0;
        *(bf16x8*)&Bs[p][sr + 64][sc] = rb1;
        __syncthreads();

        const int kn = k0 + 32;
        if (kn < 1024) {   // issue next chunk's loads; overlap compute below
            ra0 = *(const bf16x8*)(pa0 + kn);
            ra1 = *(const bf16x8*)(pa1 + kn);
            rb0 = *(const bf16x8*)(pb0 + kn);
            rb1 = *(const bf16x8*)(pb1 + kn);
        }

        bf16x8 af[4], bfr[4];
        #pragma unroll
        for (int i = 0; i < 4; ++i)
            af[i] = *(const bf16x8*)&As[p][wm * 64 + i * 16 + l16][quad * 8];
        #pragma unroll
        for (int j = 0; j < 4; ++j)
            bfr[j] = *(const bf16x8*)&Bs[p][wn * 64 + j * 16 + l16][quad * 8];
        #pragma unroll
        for (int i = 0; i < 4; ++i)
            #pragma unroll
            for (int j = 0; j < 4; ++j)
                acc[i][j] = MFMA16(af[i], bfr[j], acc[i][j]);
    }

    if (mode == 0) {
        const int z = n0 >> 10;
        const float* bias = (z == 0) ? bq : (z == 1) ? bk : bv;
        // Q scale: (1/8) * log2(e) so attn can use raw v_exp_f32 (2^x).
        const float sc2 = (z == 0) ? 0.18033688011112042f : 1.0f;
        #pragma unroll
        for (int i = 0; i < 4; ++i) {
            int row = m0 + wm * 64 + i * 16 + quad * 4;
            int b = row >> 10, s = row & 1023;
            #pragma unroll
            for (int j = 0; j < 4; ++j) {
                int n1 = (n0 + wn * 64 + j * 16 + l16) & 1023;
                int h = n1 >> 6, ch = n1 & 63;
                float bia = bias[n1];
                if (z < 2) {
                    __bf16* dst = ((z == 0) ? qb : kb)
                        + ((size_t)(b * Hh + h) * Ss + s) * Kk + ch;
                    #pragma unroll
                    for (int r = 0; r < 4; ++r)
                        dst[(size_t)r * Kk] = (__bf16)((acc[i][j][r] + bia) * sc2);
                } else {
                    bf16x4 o;
                    #pragma unroll
                    for (int r = 0; r < 4; ++r) o[r] = (__bf16)(acc[i][j][r] + bia);
                    *(bf16x4*)(vb + ((size_t)(b * Hh + h) * Kk + ch) * Ss + s) = o;
                }
            }
        }
    } else {
        #pragma unroll
        for (int i = 0; i < 4; ++i) {
            int row = m0 + wm * 64 + i * 16 + quad * 4;
            #pragma unroll
            for (int j = 0; j < 4; ++j) {
                int n = n0 + wn * 64 + j * 16 + l16;
                float bia = bo[n];
                #pragma unroll
                for (int r = 0; r < 4; ++r)
                    outf[(size_t)(row + r) * 1024 + n] = acc[i][j][r] + bia;
            }
        }
    }
}

// ---------------------------------------------------------------------------
// Flash attention: fixed-base softmax (scores bounded => no max tracking),
// wave-private P (no barrier), 32 q/wave, VGPR prefetch of next K/V tile.
// This round: ping-pong K/V LDS double-buffer -> ONE barrier per KV tile
// (gemm-proven pattern), exp2 softmax (log2e folded into Q), s_setprio
// around MFMA clusters (T5, +4-7% measured on attn).
// Mask: p = mq ? (mk ? exp(s) : 0) : 1 — exactly matches reference semantics.
// ---------------------------------------------------------------------------
__global__ __launch_bounds__(256) void attn(
    const __bf16* __restrict__ qb, const __bf16* __restrict__ kb,
    const __bf16* __restrict__ vb, const int* __restrict__ mask,
    __bf16* __restrict__ ctx)
{
    const int bh = blockIdx.x;
    const int q0 = blockIdx.y * 128;
    const int b  = bh >> 4;
    const int h  = bh & 15;
    const size_t base = (size_t)bh * Ss * Kk;

    __shared__ __align__(16) __bf16 Qs[128][72];
    __shared__ __align__(16) __bf16 Ks[2][64][72];
    __shared__ __align__(16) __bf16 VTs[2][64][72];
    __shared__ __align__(16) __bf16 Ps[4][32][72];
    __shared__ float mkf[1024];

    const int t    = threadIdx.x;
    const int wave = t >> 6, lane = t & 63;
    const int quad = lane >> 4, l16 = lane & 15;
    const int qbase = wave * 32;

    #pragma unroll
    for (int p = 0; p < 4; ++p) {
        int idx = t + p * 256;
        int r = idx >> 3, g = idx & 7;
        *(bf16x8*)&Qs[r][g * 8] =
            *(const bf16x8*)(qb + base + (size_t)(q0 + r) * Kk + g * 8);
    }
    {
        int4 mi = *(const int4*)(mask + b * Ss + t * 4);
        mkf[t * 4 + 0] = (float)mi.x;
        mkf[t * 4 + 1] = (float)mi.y;
        mkf[t * 4 + 2] = (float)mi.z;
        mkf[t * 4 + 3] = (float)mi.w;
    }

    const int r0 = t >> 3, c0 = (t & 7) * 8;
    bf16x8 kr0, kr1, vr0, vr1;
    kr0 = *(const bf16x8*)(kb + base + (size_t)(r0) * Kk + c0);
    kr1 = *(const bf16x8*)(kb + base + (size_t)(r0 + 32) * Kk + c0);
    vr0 = *(const bf16x8*)(vb + base + (size_t)(r0) * Ss + c0);
    vr1 = *(const bf16x8*)(vb + base + (size_t)(r0 + 32) * Ss + c0);

    __syncthreads();   // Qs + mkf visible

    bf16x8 aq[2][2];
    #pragma unroll
    for (int rg = 0; rg < 2; ++rg) {
        aq[rg][0] = *(const bf16x8*)&Qs[qbase + rg * 16 + l16][quad * 8];
        aq[rg][1] = *(const bf16x8*)&Qs[qbase + rg * 16 + l16][32 + quad * 8];
    }
    float mqf[2][4], omqf[2][4];
    #pragma unroll
    for (int rg = 0; rg < 2; ++rg)
        #pragma unroll
        for (int i = 0; i < 4; ++i) {
            float m = mkf[q0 + qbase + rg * 16 + quad * 4 + i];
            mqf[rg][i] = m; omqf[rg][i] = 1.0f - m;
        }

    f32x4 O[2][4];
    float lsum[2][4];
    #pragma unroll
    for (int rg = 0; rg < 2; ++rg)
        #pragma unroll
        for (int nb = 0; nb < 4; ++nb) O[rg][nb] = (f32x4){0.f, 0.f, 0.f, 0.f};
    #pragma unroll
    for (int rg = 0; rg < 2; ++rg)
        #pragma unroll
        for (int i = 0; i < 4; ++i) lsum[rg][i] = 0.f;

    for (int kt = 0; kt < Ss; kt += 64) {
        const int p = (kt >> 6) & 1;
        // write tile kt (regs prefetched last iter). Last readers of buffer p
        // were at iter kt-2, which completed before iter kt-1's barrier.
        *(bf16x8*)&Ks[p][r0][c0] = kr0;
        *(bf16x8*)&Ks[p][r0 + 32][c0] = kr1;
        *(bf16x8*)&VTs[p][r0][c0] = vr0;
        *(bf16x8*)&VTs[p][r0 + 32][c0] = vr1;
        __syncthreads();   // the ONLY barrier per tile

        int ktn = kt + 64;
        if (ktn < Ss) {    // issue next tile's loads; in flight across compute
            kr0 = *(const bf16x8*)(kb + base + (size_t)(ktn + r0) * Kk + c0);
            kr1 = *(const bf16x8*)(kb + base + (size_t)(ktn + r0 + 32) * Kk + c0);
            vr0 = *(const bf16x8*)(vb + base + (size_t)(r0) * Ss + ktn + c0);
            vr1 = *(const bf16x8*)(vb + base + (size_t)(r0 + 32) * Ss + ktn + c0);
        }

        float mkv[4];
        #pragma unroll
        for (int nb = 0; nb < 4; ++nb) mkv[nb] = mkf[kt + nb * 16 + l16];

        bf16x8 kb0[4], kb1[4];
        #pragma unroll
        for (int nb = 0; nb < 4; ++nb) {
            kb0[nb] = *(const bf16x8*)&Ks[p][nb * 16 + l16][quad * 8];
            kb1[nb] = *(const bf16x8*)&Ks[p][nb * 16 + l16][32 + quad * 8];
        }

        f32x4 s[2][4];
        __builtin_amdgcn_s_setprio(1);
        #pragma unroll
        for (int rg = 0; rg < 2; ++rg)
            #pragma unroll
            for (int nb = 0; nb < 4; ++nb) {
                f32x4 a = (f32x4){0.f, 0.f, 0.f, 0.f};
                a = MFMA16(aq[rg][0], kb0[nb], a);
                a = MFMA16(aq[rg][1], kb1[nb], a);
                s[rg][nb] = a;
            }
        __builtin_amdgcn_s_setprio(0);

        #pragma unroll
        for (int rg = 0; rg < 2; ++rg)
            #pragma unroll
            for (int i = 0; i < 4; ++i) {
                float ls = 0.f;
                #pragma unroll
                for (int nb = 0; nb < 4; ++nb) {
                    float pv = exp2_hw(s[rg][nb][i]) * mkv[nb];
                    pv = pv * mqf[rg][i] + omqf[rg][i];
                    Ps[wave][rg * 16 + quad * 4 + i][nb * 16 + l16] = (__bf16)pv;
                    ls += pv;
                }
                lsum[rg][i] += ls;
            }

        bf16x8 ap0[2], ap1[2];
        #pragma unroll
        for (int rg = 0; rg < 2; ++rg) {
            ap0[rg] = *(const bf16x8*)&Ps[wave][rg * 16 + l16][quad * 8];
            ap1[rg] = *(const bf16x8*)&Ps[wave][rg * 16 + l16][32 + quad * 8];
        }
        __builtin_amdgcn_s_setprio(1);
        #pragma unroll
        for (int nb = 0; nb < 4; ++nb) {
            bf16x8 vb0 = *(const bf16x8*)&VTs[p][nb * 16 + l16][quad * 8];
            bf16x8 vb1 = *(const bf16x8*)&VTs[p][nb * 16 + l16][32 + quad * 8];
            #pragma unroll
            for (int rg = 0; rg < 2; ++rg) {
                O[rg][nb] = MFMA16(ap0[rg], vb0, O[rg][nb]);
                O[rg][nb] = MFMA16(ap1[rg], vb1, O[rg][nb]);
            }
        }
        __builtin_amdgcn_s_setprio(0);
    }

    #pragma unroll
    for (int rg = 0; rg < 2; ++rg)
        #pragma unroll
        for (int i = 0; i < 4; ++i) {
            float l = lsum[rg][i];
            l += __shfl_xor(l, 1);
            l += __shfl_xor(l, 2);
            l += __shfl_xor(l, 4);
            l += __shfl_xor(l, 8);
            float inv = 1.0f / l;
            int srow = q0 + qbase + rg * 16 + quad * 4 + i;
            __bf16* dst = ctx + ((size_t)(b * Ss + srow) * Hh + h) * Kk;
            #pragma unroll
            for (int nb = 0; nb < 4; ++nb)
                dst[nb * 16 + l16] = (__bf16)(O[rg][nb][i] * inv);
        }
}

extern "C" void kernel_launch(void* const* d_in, const int* in_sizes, int n_in,
                              void* d_out, int out_size, void* d_ws, size_t ws_size,
                              hipStream_t stream) {
    const float* x    = (const float*)d_in[0];
    const int*   mask = (const int*)d_in[1];
    const float* Wq   = (const float*)d_in[2];
    const float* bq   = (const float*)d_in[3];
    const float* Wk   = (const float*)d_in[4];
    const float* bk   = (const float*)d_in[5];
    const float* Wv   = (const float*)d_in[6];
    const float* bv   = (const float*)d_in[7];
    const float* Wo   = (const float*)d_in[8];
    const float* bo   = (const float*)d_in[9];

    __bf16* xb   = (__bf16*)d_ws;
    __bf16* WT   = xb + XB_E;
    __bf16* WoT  = WT + WT_E;
    __bf16* qb   = WoT + WOT_E;
    __bf16* kb   = qb + QKV_E;
    __bf16* vb   = kb + QKV_E;
    __bf16* ctxb = vb + QKV_E;
    float* out = (float*)d_out;

    prep<<<dim3(16, 16, 5), 256, 0, stream>>>(x, Wq, Wk, Wv, Wo, xb, WT, WoT);
    gemm_bt<<<dim3(24, 64), 256, 0, stream>>>(xb, WT, 0, qb, kb, vb,
                                              bq, bk, bv, nullptr, nullptr);
    attn<<<dim3(128, 8), 256, 0, stream>>>(qb, kb, vb, mask, ctxb);
    gemm_bt<<<dim3(8, 64), 256, 0, stream>>>(ctxb, WoT, 1, nullptr, nullptr,
                                             nullptr, nullptr, nullptr, nullptr,
                                             out, bo);
}